// Round 6
// baseline (7033.410 us; speedup 1.0000x reference)
//
#include <hip/hip_runtime.h>

#define SS 2048
#define BATCH 512
#define NBATCH 16   // batch elems per block (fills MFMA M=16)
#define NBLK (BATCH / NBATCH)   // 32 blocks

typedef _Float16 f16x8 __attribute__((ext_vector_type(8)));  // 8 f16 (4 VGPRs)
typedef float f32x4 __attribute__((ext_vector_type(4)));     // MFMA C/D frag

#define RSC 4096.0f            // residual scale 2^12
#define RSCI 2.44140625e-4f    // 2^-12

__device__ __forceinline__ float fast_rcp(float a) { return __builtin_amdgcn_rcpf(a); }
__device__ __forceinline__ float fast_exp2(float a) { return __builtin_amdgcn_exp2f(a); }
// clamp: bit-neutral for |v| < 40 (sigmoid/tanh saturate exactly to 1.0f in
// fp32 well before 40); guarantees finite activations even on garbage input.
__device__ __forceinline__ float clamp40(float v) { return fminf(40.f, fmaxf(-40.f, v)); }
__device__ __forceinline__ float sigm(float v) {
  return fast_rcp(1.0f + fast_exp2(-1.4426950408889634f * clamp40(v)));
}
__device__ __forceinline__ float tanh_fast(float v) {
  return fmaf(-2.0f, fast_rcp(1.0f + fast_exp2(2.8853900817779268f * clamp40(v))), 1.0f);
}

__global__ void __launch_bounds__(256, 1)
lstm3_mfma(const float* __restrict__ x,
           const float* __restrict__ Wih0, const float* __restrict__ Whh0,
           const float* __restrict__ bih0, const float* __restrict__ bhh0,
           const float* __restrict__ Wih1, const float* __restrict__ Whh1,
           const float* __restrict__ bih1, const float* __restrict__ bhh1,
           const float* __restrict__ Wih2, const float* __restrict__ Whh2,
           const float* __restrict__ bih2, const float* __restrict__ bhh2,
           const float* __restrict__ fcw, const float* __restrict__ fcb,
           float* __restrict__ out) {
  // h as f16 hi + scaled f16 residual (lo = f16((h-hi)*2^12)).
  // Per (parity,layer) block: 128 f16x8 vectors = 1024 f16.
  // Element layout: elem = kc*512 + ko8*128 + m*8 + klow
  //   (unit k = kc*32 + ko8*8 + klow, batch m)
  // Lane l's A-frag (m=l&15, k=kc*32+(l>>4)*8+j) = vector [kc*64 + l]:
  // 16B-aligned by type, conflict-free wave-broadcast pattern.
  __shared__ f16x8 hHiV[2 * 3 * 128];  // 12 KB
  __shared__ f16x8 hLoV[2 * 3 * 128];  // 12 KB
  __shared__ float4 xbuf[2][NBATCH];   // x(t) staging, 512 B

  const int tid = threadIdx.x;
  const int lane = tid & 63;
  const int wid = tid >> 6;      // wave 0..3 -> owns units [wid*16, wid*16+16)
  const int q = lane >> 4;       // quad
  const int cidx = lane & 15;    // D col (unit within wave tile) / B col
  const int u = (wid << 4) + cidx;
  const int bbase = blockIdx.x * NBATCH;

  // ---- weight B-fragments in registers: B[k][n] = W[n][k] ----
  // frag elem j: k = kc*32 + q*8 + j, row = g*64 + u
  // bhi = f16(W); blo = f16((W - bhi) * 2^12)
  f16x8 bhi[5][4][2], blo[5][4][2];  // [matrix][gate][kc]
  {
    const float* Ws[5] = {Whh0, Wih1, Whh1, Wih2, Whh2};
#pragma unroll
    for (int mat = 0; mat < 5; ++mat)
#pragma unroll
      for (int g = 0; g < 4; ++g)
#pragma unroll
        for (int kc = 0; kc < 2; ++kc) {
          const float* wp = Ws[mat] + ((g << 6) + u) * 64 + kc * 32 + (q << 3);
          f16x8 h8, l8;
#pragma unroll
          for (int jj = 0; jj < 8; ++jj) {
            const float w = wp[jj];
            const _Float16 hi = (_Float16)w;
            h8[jj] = hi;
            l8[jj] = (_Float16)((w - (float)hi) * RSC);
          }
          bhi[mat][g][kc] = h8;
          blo[mat][g][kc] = l8;
        }
  }

  // per-lane fp32 biases (row g*64+u) and exact fp32 Wih0 rows
  float bsA[3][4], w0c[4][4];
#pragma unroll
  for (int g = 0; g < 4; ++g) {
    const int r = (g << 6) + u;
    bsA[0][g] = bih0[r] + bhh0[r];
    bsA[1][g] = bih1[r] + bhh1[r];
    bsA[2][g] = bih2[r] + bhh2[r];
    const float4 w0 = *(const float4*)&Wih0[r * 4];
    w0c[g][0] = w0.x; w0c[g][1] = w0.y; w0c[g][2] = w0.z; w0c[g][3] = w0.w;
  }

  // c state fp32: [layer][r], batch m = q*4+r
  float cst[3][4];
#pragma unroll
  for (int l = 0; l < 3; ++l)
#pragma unroll
    for (int r = 0; r < 4; ++r) cst[l][r] = 0.f;

  {  // zero h (both parities) and xbuf
    const f16x8 zz = {0, 0, 0, 0, 0, 0, 0, 0};
    for (int i = tid; i < 768; i += 256) { hHiV[i] = zz; hLoV[i] = zz; }
    if (tid < 2 * NBATCH) xbuf[tid >> 4][tid & 15] = make_float4(0.f, 0.f, 0.f, 0.f);
  }
  __syncthreads();
  if (tid < NBATCH)
    xbuf[0][tid] = *(const float4*)&x[(size_t)(bbase + tid) * SS * 4];
  __syncthreads();

  // epilogue write base (f16-elem units); + (plw<<10) + r*8 at use
  const int wko = ((u >> 5) << 9) + (((u >> 3) & 3) << 7) + (u & 7) + (q << 5);
  _Float16* const hS = (_Float16*)hHiV;
  _Float16* const lS = (_Float16*)hLoV;

  // gates -> activations -> c/h update -> h write (f16 hi + scaled lo)
  auto epilogue = [&](f32x4 (&a0)[4], f32x4 (&a1)[4], float (&cl)[4], int plw) {
    const int wb = (plw << 10) + wko;
#pragma unroll
    for (int r = 0; r < 4; ++r) {
      const float pi = fmaf(RSCI, a1[0][r], a0[0][r]);
      const float pf = fmaf(RSCI, a1[1][r], a0[1][r]);
      const float pg = fmaf(RSCI, a1[2][r], a0[2][r]);
      const float po = fmaf(RSCI, a1[3][r], a0[3][r]);
      const float gi = sigm(pi);
      const float gf = sigm(pf);
      const float gg = tanh_fast(pg);
      const float go = sigm(po);
      // clamp c: bit-neutral for |c| < 60 (tanh(60)==1.0f exactly in fp32)
      const float cc = fminf(60.f, fmaxf(-60.f, fmaf(gf, cl[r], gi * gg)));
      cl[r] = cc;
      const float h = go * tanh_fast(cc);
      const _Float16 hh = (_Float16)h;
      hS[wb + r * 8] = hh;
      lS[wb + r * 8] = (_Float16)((h - (float)hh) * RSC);
    }
  };

  // 3 MFMA terms per (gate,kc): Whi*hhi -> acc0; Whi*hlo + Wlo*hhi -> acc1
  auto mfma_src = [&](f32x4 (&a0)[4], f32x4 (&a1)[4], int pl, int mat) {
    const int vb = (pl << 7) + lane;
#pragma unroll
    for (int kc = 0; kc < 2; ++kc) {
      const f16x8 ah = hHiV[vb + (kc << 6)];
      const f16x8 al = hLoV[vb + (kc << 6)];
#pragma unroll
      for (int g = 0; g < 4; ++g) {
        a0[g] = __builtin_amdgcn_mfma_f32_16x16x32_f16(ah, bhi[mat][g][kc], a0[g], 0, 0, 0);
        a1[g] = __builtin_amdgcn_mfma_f32_16x16x32_f16(al, bhi[mat][g][kc], a1[g], 0, 0, 0);
        a1[g] = __builtin_amdgcn_mfma_f32_16x16x32_f16(ah, blo[mat][g][kc], a1[g], 0, 0, 0);
      }
    }
  };

  auto do_step = [&](int P, int t) {
    const int Wp = P ^ 1;
    f32x4 a0[4], a1[4];
    // ---- L0: acc0 init = bias + Wih0 * x(t) (exact fp32); acc1 = 0 ----
#pragma unroll
    for (int r = 0; r < 4; ++r) {
      const float4 xv = xbuf[P][q * 4 + r];
#pragma unroll
      for (int g = 0; g < 4; ++g) {
        float p = bsA[0][g];
        p = fmaf(w0c[g][0], xv.x, p);
        p = fmaf(w0c[g][1], xv.y, p);
        p = fmaf(w0c[g][2], xv.z, p);
        p = fmaf(w0c[g][3], xv.w, p);
        a0[g][r] = p;
        a1[g][r] = 0.f;
      }
    }
    // stage x(t+1) (readers separated by this step's barriers A+B)
    if (tid < NBATCH) {
      const int tp1 = (t + 1 < SS) ? (t + 1) : (SS - 1);
      xbuf[Wp][tid] = *(const float4*)&x[((size_t)(bbase + tid) * SS + tp1) * 4];
    }
    mfma_src(a0, a1, P * 3 + 0, 0);      // Whh0 * h0(old)
    epilogue(a0, a1, cst[0], Wp * 3 + 0);
    __syncthreads();  // barrier A
    // ---- L1 ----
#pragma unroll
    for (int g = 0; g < 4; ++g) {
      const float b1 = bsA[1][g];
#pragma unroll
      for (int r = 0; r < 4; ++r) { a0[g][r] = b1; a1[g][r] = 0.f; }
    }
    mfma_src(a0, a1, Wp * 3 + 0, 1);     // Wih1 * h0(new)
    mfma_src(a0, a1, P * 3 + 1, 2);      // Whh1 * h1(old)
    epilogue(a0, a1, cst[1], Wp * 3 + 1);
    __syncthreads();  // barrier B
    // ---- L2 ----
#pragma unroll
    for (int g = 0; g < 4; ++g) {
      const float b2 = bsA[2][g];
#pragma unroll
      for (int r = 0; r < 4; ++r) { a0[g][r] = b2; a1[g][r] = 0.f; }
    }
    mfma_src(a0, a1, Wp * 3 + 1, 3);     // Wih2 * h1(new)
    mfma_src(a0, a1, P * 3 + 2, 4);      // Whh2 * h2(old)
    epilogue(a0, a1, cst[2], Wp * 3 + 2);
    // no trailing barrier (ping-pong: next step's conflicting accesses are
    // separated by the next step's own barriers; pattern proven in r1-r3)
  };

#pragma unroll 1
  for (int t = 0; t < SS; t += 2) {
    do_step(0, t);
    do_step(1, t + 1);
  }
  __syncthreads();  // publish final h2 (parity 0 after t=2047)

  // ---- FC: out[b][o] = fc_b[o] + sum_j fc_w[o][j] * h2_last[b][j] ----
  if (tid < NBATCH * 2) {
    const int m = tid >> 1, o = tid & 1;
    float s = fcb[o];
#pragma unroll 1
    for (int j = 0; j < 64; ++j) {
      const int idx = 2 * 1024 +  // parity 0, layer 2
          ((j >> 5) << 9) + (((j >> 3) & 3) << 7) + m * 8 + (j & 7);
      const float h = (float)hS[idx] + (float)lS[idx] * RSCI;
      s = fmaf(fcw[o * 64 + j], h, s);
    }
    out[(bbase + m) * 2 + o] = s;
  }
}

extern "C" void kernel_launch(void* const* d_in, const int* in_sizes, int n_in,
                              void* d_out, int out_size, void* d_ws, size_t ws_size,
                              hipStream_t stream) {
  const float* x    = (const float*)d_in[0];
  const float* Wih0 = (const float*)d_in[1];
  const float* Whh0 = (const float*)d_in[2];
  const float* bih0 = (const float*)d_in[3];
  const float* bhh0 = (const float*)d_in[4];
  const float* Wih1 = (const float*)d_in[5];
  const float* Whh1 = (const float*)d_in[6];
  const float* bih1 = (const float*)d_in[7];
  const float* bhh1 = (const float*)d_in[8];
  const float* Wih2 = (const float*)d_in[9];
  const float* Whh2 = (const float*)d_in[10];
  const float* bih2 = (const float*)d_in[11];
  const float* bhh2 = (const float*)d_in[12];
  const float* fcw  = (const float*)d_in[13];
  const float* fcb  = (const float*)d_in[14];
  float* out = (float*)d_out;

  lstm3_mfma<<<dim3(NBLK), dim3(256), 0, stream>>>(
      x, Wih0, Whh0, bih0, bhh0, Wih1, Whh1, bih1, bhh1,
      Wih2, Whh2, bih2, bhh2, fcw, fcb, out);
}

// Round 7
// 6781.557 us; speedup vs baseline: 1.0371x; 1.0371x over previous
//
#include <hip/hip_runtime.h>

#define SS 2048
#define BATCH 512
#define NBATCH 16   // batch elems per block (fills MFMA M=16)
#define NBLK (BATCH / NBATCH)   // 32 blocks

typedef _Float16 f16x8 __attribute__((ext_vector_type(8)));  // 8 f16 (4 VGPRs)
typedef float f32x4 __attribute__((ext_vector_type(4)));     // MFMA C/D frag

#define RSC 4096.0f            // residual scale 2^12
#define RSCI 2.44140625e-4f    // 2^-12
#define K1 1.4426950408889634f // log2(e)
#define K2 2.8853900817779268f // 2*log2(e)

__device__ __forceinline__ float fast_rcp(float a) { return __builtin_amdgcn_rcpf(a); }
__device__ __forceinline__ float fast_exp2(float a) { return __builtin_amdgcn_exp2f(a); }
// |pre|>15: sigmoid/tanh within 3e-7 of saturation -> clamp is harmless and
// keeps all exp2 products finite (max ~6e27 << FLT_MAX).
__device__ __forceinline__ float clamp15(float v) { return fminf(15.f, fmaxf(-15.f, v)); }

// Barrier draining LDS only: leaves the global x-prefetch in flight
// (__syncthreads would s_waitcnt vmcnt(0) and stall every step on HBM).
__device__ __forceinline__ void bar_lds() {
  asm volatile("s_waitcnt lgkmcnt(0)\n\ts_barrier" ::: "memory");
}

__global__ void __launch_bounds__(256, 1)
lstm3_mfma(const float* __restrict__ x,
           const float* __restrict__ Wih0, const float* __restrict__ Whh0,
           const float* __restrict__ bih0, const float* __restrict__ bhh0,
           const float* __restrict__ Wih1, const float* __restrict__ Whh1,
           const float* __restrict__ bih1, const float* __restrict__ bhh1,
           const float* __restrict__ Wih2, const float* __restrict__ Whh2,
           const float* __restrict__ bih2, const float* __restrict__ bhh2,
           const float* __restrict__ fcw, const float* __restrict__ fcb,
           float* __restrict__ out) {
  // h as f16 hi + scaled f16 residual (lo = f16((h-hi)*2^12)).
  // Per (parity,layer) block: 128 f16x8 vectors = 1024 f16,
  // elem = kc*512 + ko8*128 + m*8 + klow; lane l's A-frag = vector [kc*64+l].
  __shared__ f16x8 hHiV[2 * 3 * 128];  // 12 KB
  __shared__ f16x8 hLoV[2 * 3 * 128];  // 12 KB
  __shared__ float4 xbuf[2][NBATCH];   // x(t) ring, 512 B

  const int tid = threadIdx.x;
  const int lane = tid & 63;
  const int wid = tid >> 6;
  const int q = lane >> 4;
  const int cidx = lane & 15;
  const int u = (wid << 4) + cidx;
  const int bbase = blockIdx.x * NBATCH;

  // ---- weight B-fragments in registers (hi + scaled-lo f16 split) ----
  f16x8 bhi[5][4][2], blo[5][4][2];  // [matrix][gate][kc]
  {
    const float* Ws[5] = {Whh0, Wih1, Whh1, Wih2, Whh2};
#pragma unroll
    for (int mat = 0; mat < 5; ++mat)
#pragma unroll
      for (int g = 0; g < 4; ++g)
#pragma unroll
        for (int kc = 0; kc < 2; ++kc) {
          const float* wp = Ws[mat] + ((g << 6) + u) * 64 + kc * 32 + (q << 3);
          f16x8 h8, l8;
#pragma unroll
          for (int jj = 0; jj < 8; ++jj) {
            const float w = wp[jj];
            const _Float16 hi = (_Float16)w;
            h8[jj] = hi;
            l8[jj] = (_Float16)((w - (float)hi) * RSC);
          }
          bhi[mat][g][kc] = h8;
          blo[mat][g][kc] = l8;
        }
  }

  float bsA[3][4], w0c[4][4];
#pragma unroll
  for (int g = 0; g < 4; ++g) {
    const int r = (g << 6) + u;
    bsA[0][g] = bih0[r] + bhh0[r];
    bsA[1][g] = bih1[r] + bhh1[r];
    bsA[2][g] = bih2[r] + bhh2[r];
    const float4 w0 = *(const float4*)&Wih0[r * 4];
    w0c[g][0] = w0.x; w0c[g][1] = w0.y; w0c[g][2] = w0.z; w0c[g][3] = w0.w;
  }

  float cst[3][4];
#pragma unroll
  for (int l = 0; l < 3; ++l)
#pragma unroll
    for (int r = 0; r < 4; ++r) cst[l][r] = 0.f;

  {
    const f16x8 zz = {0, 0, 0, 0, 0, 0, 0, 0};
    for (int i = tid; i < 768; i += 256) { hHiV[i] = zz; hLoV[i] = zz; }
  }
  // x prologue: xbuf[0] = x(0); xr = x(1) (register buffer, wave0 lanes 0-15)
  float4 xr = make_float4(0.f, 0.f, 0.f, 0.f);
  if (tid < NBATCH) {
    xbuf[0][tid] = *(const float4*)&x[(size_t)(bbase + tid) * SS * 4];
    xr = *(const float4*)&x[((size_t)(bbase + tid) * SS + 1) * 4];
  }
  __syncthreads();  // full barrier OK in prologue

  const int wko = ((u >> 5) << 9) + (((u >> 3) & 3) << 7) + (u & 7) + (q << 5);
  _Float16* const hS = (_Float16*)hHiV;
  _Float16* const lS = (_Float16*)hLoV;

  // --- helpers ---
  auto initb = [&](f32x4 (&A0)[4], f32x4 (&A1)[4], int L) {
#pragma unroll
    for (int g = 0; g < 4; ++g) {
      const float b = bsA[L][g];
      A0[g][0] = b; A0[g][1] = b; A0[g][2] = b; A0[g][3] = b;
      A1[g][0] = 0.f; A1[g][1] = 0.f; A1[g][2] = 0.f; A1[g][3] = 0.f;
    }
  };

  // one source matrix: Whi*hhi -> A0; Whi*hlo + Wlo*hhi -> A1
  auto mfma_mat = [&](f32x4 (&A0)[4], f32x4 (&A1)[4], int pl, int mat) {
    const int vb = (pl << 7) + lane;
    const f16x8 ah0 = hHiV[vb],      al0 = hLoV[vb];
    const f16x8 ah1 = hHiV[vb + 64], al1 = hLoV[vb + 64];
#pragma unroll
    for (int g = 0; g < 4; ++g) {
      A0[g] = __builtin_amdgcn_mfma_f32_16x16x32_f16(ah0, bhi[mat][g][0], A0[g], 0, 0, 0);
      A0[g] = __builtin_amdgcn_mfma_f32_16x16x32_f16(ah1, bhi[mat][g][1], A0[g], 0, 0, 0);
      A1[g] = __builtin_amdgcn_mfma_f32_16x16x32_f16(al0, bhi[mat][g][0], A1[g], 0, 0, 0);
      A1[g] = __builtin_amdgcn_mfma_f32_16x16x32_f16(ah0, blo[mat][g][0], A1[g], 0, 0, 0);
      A1[g] = __builtin_amdgcn_mfma_f32_16x16x32_f16(al1, bhi[mat][g][1], A1[g], 0, 0, 0);
      A1[g] = __builtin_amdgcn_mfma_f32_16x16x32_f16(ah1, blo[mat][g][1], A1[g], 0, 0, 0);
    }
  };

  // gates -> c/h (shared-denominator rational form; 7 trans per (m,u)).
  // c' = [ef(ei+1)(G+1)c + ei(G-1)(ef+1)] / [(ef+1)(ei+1)(G+1)]
  //    = sig(f)*c + sig(i)*tanh(g);   h = eo(C2-1)/[(eo+1)(C2+1)] = sig(o)*tanh(c')
  auto epi = [&](f32x4 (&A0)[4], f32x4 (&A1)[4], float (&cl)[4], int plw,
                 bool addx, int P) {
    float4 xv[4];
    if (addx) {
#pragma unroll
      for (int r = 0; r < 4; ++r) xv[r] = xbuf[P][q * 4 + r];
    }
    const int wb = (plw << 10) + wko;
#pragma unroll
    for (int r = 0; r < 4; ++r) {
      float pre[4];
#pragma unroll
      for (int g = 0; g < 4; ++g) {
        float p = fmaf(RSCI, A1[g][r], A0[g][r]);
        if (addx) {
          p = fmaf(w0c[g][0], xv[r].x, p);
          p = fmaf(w0c[g][1], xv[r].y, p);
          p = fmaf(w0c[g][2], xv[r].z, p);
          p = fmaf(w0c[g][3], xv[r].w, p);
        }
        pre[g] = p;
      }
      const float ei = fast_exp2(K1 * clamp15(pre[0]));
      const float ef = fast_exp2(K1 * clamp15(pre[1]));
      const float G  = fast_exp2(K2 * clamp15(pre[2]));
      const float eo = fast_exp2(K1 * clamp15(pre[3]));
      const float e1 = ei + 1.f, f1 = ef + 1.f, G1 = G + 1.f, Gm = G - 1.f, o1 = eo + 1.f;
      const float rd = fast_rcp(f1 * e1 * G1);
      const float t1 = ef * e1 * G1 * cl[r];
      const float t2 = ei * Gm * f1;
      float cn = (t1 + t2) * rd;
      cn = fminf(40.f, fmaxf(-40.f, cn));  // tanh exact beyond 19; keeps C2 finite
      cl[r] = cn;
      const float C2 = fast_exp2(K2 * cn);
      const float h = eo * (C2 - 1.f) * fast_rcp(o1 * (C2 + 1.f));
      const _Float16 hh = (_Float16)h;
      hS[wb + r * 8] = hh;
      lS[wb + r * 8] = (_Float16)((h - (float)hh) * RSC);
    }
  };

  // aacc persists across steps: phase2 of step t computes Whh0*h0(new) for t+1
  f32x4 a0[4], a1[4];
  initb(a0, a1, 0);  // step 0: Whh0*h0_init = 0, so just bias

  auto do_step = [&](int P, int t) {
    const int W = P ^ 1;
    // ---- phase 0 ----
    if (tid < NBATCH) {
      xbuf[W][tid] = xr;  // x(t+1) -> LDS (auto vmcnt wait; load ~1 step old)
      const int tp2 = (t + 2 < SS) ? (t + 2) : (SS - 1);
      xr = *(const float4*)&x[((size_t)(bbase + tid) * SS + tp2) * 4];
    }
    f32x4 b0[4], b1[4];
    initb(b0, b1, 1);
    mfma_mat(b0, b1, P * 3 + 1, 2);      // Whh1 * h1(old)  [hoisted]
    epi(a0, a1, cst[0], W * 3 + 0, true, P);  // L0 epilogue -> h0(new)
    bar_lds();  // barrier A
    // ---- phase 1 ----
    mfma_mat(b0, b1, W * 3 + 0, 1);      // Wih1 * h0(new)
    f32x4 c0[4], c1[4];
    initb(c0, c1, 2);
    mfma_mat(c0, c1, P * 3 + 2, 4);      // Whh2 * h2(old)  [hoisted]
    epi(b0, b1, cst[1], W * 3 + 1, false, P);  // L1 -> h1(new)
    bar_lds();  // barrier B
    // ---- phase 2 ----
    mfma_mat(c0, c1, W * 3 + 1, 3);      // Wih2 * h1(new)
    initb(a0, a1, 0);
    mfma_mat(a0, a1, W * 3 + 0, 0);      // Whh0 * h0(new) [for NEXT step L0]
    epi(c0, c1, cst[2], W * 3 + 2, false, P);  // L2 -> h2(new)
    // no trailing barrier: h2(new)/h1(new) readers in step t+1 are separated
    // by step t's barrier B or step t+1's barrier A (full hazard walk done)
  };

#pragma unroll 1
  for (int t = 0; t < SS; t += 2) {
    do_step(0, t);
    do_step(1, t + 1);
  }
  __syncthreads();  // publish final h2 (parity 0 after t=2047)

  // ---- FC: out[b][o] = fc_b[o] + sum_j fc_w[o][j] * h2_last[b][j] ----
  if (tid < NBATCH * 2) {
    const int m = tid >> 1, o = tid & 1;
    float s = fcb[o];
#pragma unroll 1
    for (int j = 0; j < 64; ++j) {
      const int idx = 2 * 1024 +  // parity 0, layer 2
          ((j >> 5) << 9) + (((j >> 3) & 3) << 7) + m * 8 + (j & 7);
      const float h = (float)hS[idx] + (float)lS[idx] * RSCI;
      s = fmaf(fcw[o * 64 + j], h, s);
    }
    out[(bbase + m) * 2 + o] = s;
  }
}

extern "C" void kernel_launch(void* const* d_in, const int* in_sizes, int n_in,
                              void* d_out, int out_size, void* d_ws, size_t ws_size,
                              hipStream_t stream) {
  const float* x    = (const float*)d_in[0];
  const float* Wih0 = (const float*)d_in[1];
  const float* Whh0 = (const float*)d_in[2];
  const float* bih0 = (const float*)d_in[3];
  const float* bhh0 = (const float*)d_in[4];
  const float* Wih1 = (const float*)d_in[5];
  const float* Whh1 = (const float*)d_in[6];
  const float* bih1 = (const float*)d_in[7];
  const float* bhh1 = (const float*)d_in[8];
  const float* Wih2 = (const float*)d_in[9];
  const float* Whh2 = (const float*)d_in[10];
  const float* bih2 = (const float*)d_in[11];
  const float* bhh2 = (const float*)d_in[12];
  const float* fcw  = (const float*)d_in[13];
  const float* fcb  = (const float*)d_in[14];
  float* out = (float*)d_out;

  lstm3_mfma<<<dim3(NBLK), dim3(256), 0, stream>>>(
      x, Wih0, Whh0, bih0, bhh0, Wih1, Whh1, bih1, bhh1,
      Wih2, Whh2, bih2, bhh2, fcw, fcb, out);
}

// Round 8
// 6510.278 us; speedup vs baseline: 1.0804x; 1.0417x over previous
//
#include <hip/hip_runtime.h>

#define SS 2048
#define BATCH 512
#define NBATCH 16   // batch elems per block (fills MFMA M=16)
#define NBLK (BATCH / NBATCH)   // 32 blocks

typedef _Float16 f16x8 __attribute__((ext_vector_type(8)));  // 8 f16 (4 VGPRs)
typedef float f32x4 __attribute__((ext_vector_type(4)));     // MFMA C/D frag

#define RSC 4096.0f            // residual scale 2^12
#define RSCI 2.44140625e-4f    // 2^-12
#define K1 1.4426950408889634f // log2(e)
#define K2 2.8853900817779268f // 2*log2(e)

__device__ __forceinline__ float fast_rcp(float a) { return __builtin_amdgcn_rcpf(a); }
__device__ __forceinline__ float fast_exp2(float a) { return __builtin_amdgcn_exp2f(a); }
__device__ __forceinline__ float clamp15(float v) { return fminf(15.f, fmaxf(-15.f, v)); }

// LDS-only barrier (keeps the global x-prefetch in flight)
__device__ __forceinline__ void bar_lds() {
  asm volatile("s_waitcnt lgkmcnt(0)\n\ts_barrier" ::: "memory");
}

struct FragSet { f16x8 h0, h1, l0, l1; };  // hi/lo A-frags for kc=0,1

__global__ void __launch_bounds__(256, 1)
lstm3_mfma(const float* __restrict__ x,
           const float* __restrict__ Wih0, const float* __restrict__ Whh0,
           const float* __restrict__ bih0, const float* __restrict__ bhh0,
           const float* __restrict__ Wih1, const float* __restrict__ Whh1,
           const float* __restrict__ bih1, const float* __restrict__ bhh1,
           const float* __restrict__ Wih2, const float* __restrict__ Whh2,
           const float* __restrict__ bih2, const float* __restrict__ bhh2,
           const float* __restrict__ fcw, const float* __restrict__ fcb,
           float* __restrict__ out) {
  // h as f16 hi + scaled f16 residual. Parity rule: h0(t),h1(t),h2(t) live at
  // parity (t&1). Per (parity,layer) block: 128 f16x8 vectors; lane l's
  // A-frag = vector [kc*64 + l] (16B aligned, conflict-free broadcast).
  __shared__ f16x8 hHiV[2 * 3 * 128];  // 12 KB
  __shared__ f16x8 hLoV[2 * 3 * 128];  // 12 KB
  __shared__ float4 xbuf[2][NBATCH];   // x ring: xbuf[(τ)&1] holds x(τ)

  const int tid = threadIdx.x;
  const int lane = tid & 63;
  const int wid = tid >> 6;
  const int q = lane >> 4;
  const int cidx = lane & 15;
  const int u = (wid << 4) + cidx;
  const int bbase = blockIdx.x * NBATCH;

  // ---- weight B-fragments in registers (hi + scaled-lo f16 split) ----
  f16x8 bhi[5][4][2], blo[5][4][2];  // [matrix][gate][kc]
  {
    const float* Ws[5] = {Whh0, Wih1, Whh1, Wih2, Whh2};
#pragma unroll
    for (int mat = 0; mat < 5; ++mat)
#pragma unroll
      for (int g = 0; g < 4; ++g)
#pragma unroll
        for (int kc = 0; kc < 2; ++kc) {
          const float* wp = Ws[mat] + ((g << 6) + u) * 64 + kc * 32 + (q << 3);
          f16x8 h8, l8;
#pragma unroll
          for (int jj = 0; jj < 8; ++jj) {
            const float w = wp[jj];
            const _Float16 hi = (_Float16)w;
            h8[jj] = hi;
            l8[jj] = (_Float16)((w - (float)hi) * RSC);
          }
          bhi[mat][g][kc] = h8;
          blo[mat][g][kc] = l8;
        }
  }

  float bsA[3][4], w0c[4][4];
#pragma unroll
  for (int g = 0; g < 4; ++g) {
    const int r = (g << 6) + u;
    bsA[0][g] = bih0[r] + bhh0[r];
    bsA[1][g] = bih1[r] + bhh1[r];
    bsA[2][g] = bih2[r] + bhh2[r];
    const float4 w0 = *(const float4*)&Wih0[r * 4];
    w0c[g][0] = w0.x; w0c[g][1] = w0.y; w0c[g][2] = w0.z; w0c[g][3] = w0.w;
  }

  float cst[3][4];
#pragma unroll
  for (int l = 0; l < 3; ++l)
#pragma unroll
    for (int r = 0; r < 4; ++r) cst[l][r] = 0.f;

  {
    const f16x8 zz = {0, 0, 0, 0, 0, 0, 0, 0};
    for (int i = tid; i < 768; i += 256) { hHiV[i] = zz; hLoV[i] = zz; }
  }
  float4 xr = make_float4(0.f, 0.f, 0.f, 0.f);
  if (tid < NBATCH) {
    const size_t rowb = (size_t)(bbase + tid) * SS;
    xbuf[0][tid] = *(const float4*)&x[rowb * 4];            // x(0)
    xbuf[1][tid] = *(const float4*)&x[(rowb + 1) * 4];      // x(1)
    xr = *(const float4*)&x[(rowb + 2) * 4];                // x(2)
  }

  const int wko = ((u >> 5) << 9) + (((u >> 3) & 3) << 7) + (u & 7) + (q << 5);
  _Float16* const hS = (_Float16*)hHiV;
  _Float16* const lS = (_Float16*)hLoV;

  auto initb = [&](f32x4 (&A0)[4], f32x4 (&A1)[4], int L) {
#pragma unroll
    for (int g = 0; g < 4; ++g) {
      const float b = bsA[L][g];
      A0[g][0] = b; A0[g][1] = b; A0[g][2] = b; A0[g][3] = b;
      A1[g][0] = 0.f; A1[g][1] = 0.f; A1[g][2] = 0.f; A1[g][3] = 0.f;
    }
  };

  auto ldfrags = [&](int pl) {
    const int vb = (pl << 7) + lane;
    FragSet s;
    s.h0 = hHiV[vb]; s.h1 = hHiV[vb + 64];
    s.l0 = hLoV[vb]; s.l1 = hLoV[vb + 64];
    return s;
  };

  auto mfma_fs = [&](f32x4 (&A0)[4], f32x4 (&A1)[4], const FragSet& s, int mat) {
#pragma unroll
    for (int g = 0; g < 4; ++g) {
      A0[g] = __builtin_amdgcn_mfma_f32_16x16x32_f16(s.h0, bhi[mat][g][0], A0[g], 0, 0, 0);
      A0[g] = __builtin_amdgcn_mfma_f32_16x16x32_f16(s.h1, bhi[mat][g][1], A0[g], 0, 0, 0);
      A1[g] = __builtin_amdgcn_mfma_f32_16x16x32_f16(s.l0, bhi[mat][g][0], A1[g], 0, 0, 0);
      A1[g] = __builtin_amdgcn_mfma_f32_16x16x32_f16(s.h0, blo[mat][g][0], A1[g], 0, 0, 0);
      A1[g] = __builtin_amdgcn_mfma_f32_16x16x32_f16(s.l1, bhi[mat][g][1], A1[g], 0, 0, 0);
      A1[g] = __builtin_amdgcn_mfma_f32_16x16x32_f16(s.h1, blo[mat][g][1], A1[g], 0, 0, 0);
    }
  };

  // r6/r7-proven rational epilogue (7 trans/(m,u)), NaN-fenced clamps.
  auto epi = [&](f32x4 (&A0)[4], f32x4 (&A1)[4], float (&cl)[4], int plw,
                 bool addx, int xP) {
    float4 xv[4];
    if (addx) {
#pragma unroll
      for (int r = 0; r < 4; ++r) xv[r] = xbuf[xP][q * 4 + r];
    }
    const int wb = (plw << 10) + wko;
#pragma unroll
    for (int r = 0; r < 4; ++r) {
      float pre[4];
#pragma unroll
      for (int g = 0; g < 4; ++g) {
        float p = fmaf(RSCI, A1[g][r], A0[g][r]);
        if (addx) {
          p = fmaf(w0c[g][0], xv[r].x, p);
          p = fmaf(w0c[g][1], xv[r].y, p);
          p = fmaf(w0c[g][2], xv[r].z, p);
          p = fmaf(w0c[g][3], xv[r].w, p);
        }
        pre[g] = p;
      }
      const float ei = fast_exp2(K1 * clamp15(pre[0]));
      const float ef = fast_exp2(K1 * clamp15(pre[1]));
      const float G  = fast_exp2(K2 * clamp15(pre[2]));
      const float eo = fast_exp2(K1 * clamp15(pre[3]));
      const float e1 = ei + 1.f, f1 = ef + 1.f, G1 = G + 1.f, Gm = G - 1.f, o1 = eo + 1.f;
      const float rd = fast_rcp(f1 * e1 * G1);
      const float t1 = ef * e1 * G1 * cl[r];
      const float t2 = ei * Gm * f1;
      float cn = (t1 + t2) * rd;
      cn = fminf(40.f, fmaxf(-40.f, cn));
      cl[r] = cn;
      const float C2 = fast_exp2(K2 * cn);
      const float h = eo * (C2 - 1.f) * fast_rcp(o1 * (C2 + 1.f));
      const _Float16 hh = (_Float16)h;
      hS[wb + r * 8] = hh;
      lS[wb + r * 8] = (_Float16)((h - (float)hh) * RSC);
    }
  };

  __syncthreads();
  // ---- prologue: h0(0) = act(bias0 + Wih0*x(0)), parity 0 ----
  {
    f32x4 a0[4], a1[4];
    initb(a0, a1, 0);
    epi(a0, a1, cst[0], 0 /*par0,L0*/, true, 0);
  }
  FragSet fh1;  // carried h1(t-1) frags; h1(-1) = 0
  {
    const f16x8 zz = {0, 0, 0, 0, 0, 0, 0, 0};
    fh1.h0 = zz; fh1.h1 = zz; fh1.l0 = zz; fh1.l1 = zz;
  }
  __syncthreads();

  // Two-phase step. All write->read pairs across phases/steps separated by
  // >=1 barrier (hazard walk in analysis); h0/h1 frags reused via registers.
  auto do_step = [&](auto Pc, int t) {
    constexpr int P = decltype(Pc)::value;
    constexpr int Q = P ^ 1;
    // ---- phase 1: h1(t) ----
    const FragSet f0 = ldfrags(P * 3 + 0);       // h0(t)  [written ph2(t-1)]
    f32x4 b0[4], b1[4];
    initb(b0, b1, 1);
    mfma_fs(b0, b1, f0, 1);                      // Wih1 * h0(t)
    mfma_fs(b0, b1, fh1, 2);                     // Whh1 * h1(t-1)  [regs]
    epi(b0, b1, cst[1], P * 3 + 1, false, 0);    // write h1(t) @ par P
    bar_lds();
    // ---- phase 2: h2(t) + h0(t+1) ----
    const FragSet f1n = ldfrags(P * 3 + 1);      // h1(t)   -> carry
    const FragSet f2o = ldfrags(Q * 3 + 2);      // h2(t-1)
    f32x4 c0[4], c1[4];
    initb(c0, c1, 2);
    mfma_fs(c0, c1, f2o, 4);                     // Whh2 * h2(t-1)
    mfma_fs(c0, c1, f1n, 3);                     // Wih2 * h1(t)
    f32x4 a0[4], a1[4];
    initb(a0, a1, 0);
    mfma_fs(a0, a1, f0, 0);                      // Whh0 * h0(t)  [regs reuse]
    epi(c0, c1, cst[2], P * 3 + 2, false, 0);    // write h2(t) @ par P
    epi(a0, a1, cst[0], Q * 3 + 0, true, Q);     // write h0(t+1) @ par Q
    if (tid < NBATCH) {
      xbuf[P][tid] = xr;                         // x(t+2) -> slot (t+2)&1 == P
      const int tp = (t + 3 < SS) ? (t + 3) : (SS - 1);
      xr = *(const float4*)&x[((size_t)(bbase + tid) * SS + tp) * 4];
    }
    fh1 = f1n;
    bar_lds();
  };

#pragma unroll 1
  for (int t = 0; t < SS; t += 2) {
    do_step(std::integral_constant<int, 0>{}, t);
    do_step(std::integral_constant<int, 1>{}, t + 1);
  }
  __syncthreads();

  // ---- FC: h2(2047) lives at parity 1, layer 2 (pl=5) ----
  if (tid < NBATCH * 2) {
    const int m = tid >> 1, o = tid & 1;
    float s = fcb[o];
#pragma unroll 1
    for (int j = 0; j < 64; ++j) {
      const int idx = (5 << 10) +
          ((j >> 5) << 9) + (((j >> 3) & 3) << 7) + m * 8 + (j & 7);
      const float h = (float)hS[idx] + (float)lS[idx] * RSCI;
      s = fmaf(fcw[o * 64 + j], h, s);
    }
    out[(bbase + m) * 2 + o] = s;
  }
}

extern "C" void kernel_launch(void* const* d_in, const int* in_sizes, int n_in,
                              void* d_out, int out_size, void* d_ws, size_t ws_size,
                              hipStream_t stream) {
  const float* x    = (const float*)d_in[0];
  const float* Wih0 = (const float*)d_in[1];
  const float* Whh0 = (const float*)d_in[2];
  const float* bih0 = (const float*)d_in[3];
  const float* bhh0 = (const float*)d_in[4];
  const float* Wih1 = (const float*)d_in[5];
  const float* Whh1 = (const float*)d_in[6];
  const float* bih1 = (const float*)d_in[7];
  const float* bhh1 = (const float*)d_in[8];
  const float* Wih2 = (const float*)d_in[9];
  const float* Whh2 = (const float*)d_in[10];
  const float* bih2 = (const float*)d_in[11];
  const float* bhh2 = (const float*)d_in[12];
  const float* fcw  = (const float*)d_in[13];
  const float* fcb  = (const float*)d_in[14];
  float* out = (float*)d_out;

  lstm3_mfma<<<dim3(NBLK), dim3(256), 0, stream>>>(
      x, Wih0, Whh0, bih0, bhh0, Wih1, Whh1, bih1, bhh1,
      Wih2, Whh2, bih2, bhh2, fcw, fcb, out);
}